// Round 4
// baseline (320.522 us; speedup 1.0000x reference)
//
#include <hip/hip_runtime.h>
#include <stdint.h>

#define NTOK   16384      // B*T = 4*4096
#define DM     1024
#define DI     512
#define NH     8
#define DH     64
#define CHUNK  64
#define NCH    64         // T / CHUNK
#define NBHC   2048       // B*H*NCH

using short8 = __attribute__((ext_vector_type(8))) short;
using f32x4  = __attribute__((ext_vector_type(4))) float;

__device__ __forceinline__ unsigned short f2bf(float f) {
  union { float f; unsigned int u; } x; x.f = f;
  unsigned int u = x.u;
  return (unsigned short)((u + 0x7fffu + ((u >> 16) & 1u)) >> 16);
}
__device__ __forceinline__ float bf2f(unsigned short h) {
  union { unsigned int u; float f; } x; x.u = ((unsigned int)h) << 16; return x.f;
}

typedef const __attribute__((address_space(1))) void* gp1_t;
typedef __attribute__((address_space(3))) void* lp3_t;
__device__ __forceinline__ void gload_lds16(const void* g, void* l) {
  __builtin_amdgcn_global_load_lds((gp1_t)g, (lp3_t)l, 16, 0, 0);
}

// ---------------- K0: fused init: LN (blocks 0..16383), W transposes ---------
__global__ __launch_bounds__(256) void init_kernel(const float* __restrict__ x,
                                                   const float* __restrict__ gamma,
                                                   const float* __restrict__ beta,
                                                   const float* __restrict__ Wq,
                                                   const float* __restrict__ Wk,
                                                   const float* __restrict__ Wv,
                                                   const float* __restrict__ Wa,
                                                   const float* __restrict__ Wo,
                                                   unsigned short* __restrict__ xn,
                                                   unsigned short* __restrict__ Wt,
                                                   unsigned short* __restrict__ Wot) {
  const int blk = blockIdx.x, tid = threadIdx.x;
  __shared__ float tile[32][33];
  __shared__ float rs_[4], rss_[4];
  if (blk < NTOK) {
    const int row = blk;
    float4 v = ((const float4*)(x + (long)row * DM))[tid];
    float s  = v.x + v.y + v.z + v.w;
    float ss = v.x * v.x + v.y * v.y + v.z * v.z + v.w * v.w;
    #pragma unroll
    for (int off = 32; off > 0; off >>= 1) { s += __shfl_down(s, off); ss += __shfl_down(ss, off); }
    int wave = tid >> 6, lane = tid & 63;
    if (lane == 0) { rs_[wave] = s; rss_[wave] = ss; }
    __syncthreads();
    s  = rs_[0] + rs_[1] + rs_[2] + rs_[3];
    ss = rss_[0] + rss_[1] + rss_[2] + rss_[3];
    float mu   = s * (1.f / DM);
    float var  = ss * (1.f / DM) - mu * mu;
    float rstd = rsqrtf(var + 1e-5f);
    int idx = tid * 4;
    float xv[4] = {v.x, v.y, v.z, v.w};
    unsigned short o[4];
    #pragma unroll
    for (int j = 0; j < 4; ++j) o[j] = f2bf((xv[j] - mu) * rstd * gamma[idx + j] + beta[idx + j]);
    uint2 pk; pk.x = (unsigned)o[0] | ((unsigned)o[1] << 16); pk.y = (unsigned)o[2] | ((unsigned)o[3] << 16);
    *(uint2*)(xn + (long)row * DM + idx) = pk;
  } else if (blk < NTOK + 2048) {
    const int id = blk - NTOK;
    const int z = id >> 9, r9 = id & 511;
    const float* in = (z == 0) ? Wq : (z == 1) ? Wk : (z == 2) ? Wv : Wa;
    unsigned short* o = Wt + (size_t)z * 512 * 1024;
    int bx = (r9 & 15) * 32, by = (r9 >> 4) * 32;
    int tx = tid & 31, ty = tid >> 5;
    #pragma unroll
    for (int r = ty; r < 32; r += 8) tile[r][tx] = in[(long)(by + r) * 512 + bx + tx];
    __syncthreads();
    #pragma unroll
    for (int r = ty; r < 32; r += 8) o[(long)(bx + r) * 1024 + by + tx] = f2bf(tile[tx][r]);
  } else {
    const int id = blk - NTOK - 2048;
    int bx = (id & 31) * 32, by = (id >> 5) * 32;
    int tx = tid & 31, ty = tid >> 5;
    #pragma unroll
    for (int r = ty; r < 32; r += 8) tile[r][tx] = Wo[(long)(by + r) * 1024 + bx + tx];
    __syncthreads();
    #pragma unroll
    for (int r = ty; r < 32; r += 8) Wot[(long)(bx + r) * 512 + by + tx] = f2bf(tile[tx][r]);
  }
}

// ---------------- GEMM: C[M][N] = A(bf16 MxK) * Bt(bf16 NxK)^T ---------------
// 256x256 tile, BK=32, QUAD-buffered LDS (4 x 32 KiB) -> prefetch depth 3.
// T3+T4+T5 combined: per K-tile TWO m201-style phases, each
//   {8/4 ds_read || 2 gload_lds -> barrier -> lgkmcnt(0)+sched_barrier ->
//    setprio(1) -> 16 MFMA -> setprio(0) -> barrier},
// counted vmcnt(8) ONLY at tile boundaries (ladder 8..8,4,0,0) -- never a
// steady-state drain-0.  512 threads = 8 waves (2M x 4N), 128x64 out/wave.
// Swizzle (verified round 3): phys_col = logical ^ (((row>>1)&3)<<4), applied
// on global staging source + ds_read address; gload_lds dest linear.
#define EPSW 264   // epilogue LDS row stride (ushorts), 256+8
#define G4_TILE(T_, DOSTAGE_, WAITC_)                                         \
  {                                                                           \
    const unsigned short* cb_ = &sm[((T_) & 3) * 16384];                      \
    unsigned short* sb_ = &sm[(((T_) + 3) & 3) * 16384];                      \
    const long ko_ = (long)((T_) + 3) * 32;                                   \
    short8 av_[4], bv_[4];                                                    \
    /* ---------- phase A: m-frags 0-3 x n-frags 0-3 ---------- */            \
    _Pragma("unroll")                                                         \
    for (int mt = 0; mt < 4; ++mt) av_[mt] = *(const short8*)&cb_[aoff + mt * 512]; \
    _Pragma("unroll")                                                         \
    for (int nt = 0; nt < 4; ++nt) bv_[nt] = *(const short8*)&cb_[boff + nt * 512]; \
    if (DOSTAGE_) {                                                           \
      gload_lds16(a0p + ko_, sb_ + dst);                                      \
      gload_lds16(a1p + ko_, sb_ + 4096 + dst);                               \
    }                                                                         \
    __builtin_amdgcn_s_barrier();                                             \
    asm volatile("s_waitcnt lgkmcnt(0)" ::: "memory");                        \
    __builtin_amdgcn_sched_barrier(0);                                        \
    __builtin_amdgcn_s_setprio(1);                                            \
    _Pragma("unroll")                                                         \
    for (int mt = 0; mt < 4; ++mt)                                            \
      _Pragma("unroll")                                                       \
      for (int nt = 0; nt < 4; ++nt)                                          \
        acc[mt][nt] = __builtin_amdgcn_mfma_f32_16x16x32_bf16(av_[mt], bv_[nt], acc[mt][nt], 0, 0, 0); \
    __builtin_amdgcn_s_setprio(0);                                            \
    __builtin_amdgcn_s_barrier();                                             \
    /* ---------- phase B: m-frags 4-7 x n-frags 0-3 ---------- */            \
    _Pragma("unroll")                                                         \
    for (int mt = 0; mt < 4; ++mt) av_[mt] = *(const short8*)&cb_[aoff + 2048 + mt * 512]; \
    if (DOSTAGE_) {                                                           \
      gload_lds16(b0p + ko_, sb_ + 8192 + dst);                               \
      gload_lds16(b1p + ko_, sb_ + 12288 + dst);                              \
    }                                                                         \
    __builtin_amdgcn_s_barrier();                                             \
    asm volatile("s_waitcnt lgkmcnt(0)" ::: "memory");                        \
    __builtin_amdgcn_sched_barrier(0);                                        \
    __builtin_amdgcn_s_setprio(1);                                            \
    _Pragma("unroll")                                                         \
    for (int mt = 0; mt < 4; ++mt)                                            \
      _Pragma("unroll")                                                       \
      for (int nt = 0; nt < 4; ++nt)                                          \
        acc[4 + mt][nt] = __builtin_amdgcn_mfma_f32_16x16x32_bf16(av_[mt], bv_[nt], acc[4 + mt][nt], 0, 0, 0); \
    __builtin_amdgcn_s_setprio(0);                                            \
    asm volatile("s_waitcnt " WAITC_ ::: "memory");                           \
    __builtin_amdgcn_s_barrier();                                             \
    __builtin_amdgcn_sched_barrier(0);                                        \
  }

template <int MODE>
__global__ __launch_bounds__(512, 2) void gemm4s(const unsigned short* __restrict__ A,
                                                 const unsigned short* __restrict__ Bt,
                                                 unsigned short* __restrict__ Cb,
                                                 float* __restrict__ Cf,
                                                 const float* __restrict__ resid,
                                                 int M, int N, int K) {
  __shared__ __align__(16) unsigned short sm[65536];   // 128 KiB
  const int tid = threadIdx.x;
  const int wave = tid >> 6, lane = tid & 63;
  const int quad = lane >> 4, l16 = lane & 15;
  const int wm = wave >> 2, wn = wave & 3;

  // T1: bijective XCD swizzle; n-major chunks -> each XCD reuses one B panel
  const int nwg = gridDim.x;
  const int cpx = nwg >> 3;
  const int bid = blockIdx.x;
  const int swz = (bid & 7) * cpx + (bid >> 3);
  const int m0 = (swz & 63) * 256;
  const int n0 = (swz >> 6) * 256;

  // staging: thread stages 16B; dest linear (row = tid>>2 within 128-row round,
  // phys col ushort = (tid&3)*8); source col = phys ^ (((row>>1)&3)*8)
  const int r2 = tid >> 2;
  const int scol = ((tid & 3) * 8) ^ (((tid >> 3) & 3) * 8);   // ushort units, < 32
  const unsigned short* a0p = A + (long)(m0 + r2) * K + scol;
  const unsigned short* a1p = A + (long)(m0 + 128 + r2) * K + scol;
  const unsigned short* b0p = Bt + (long)(n0 + r2) * K + scol;
  const unsigned short* b1p = Bt + (long)(n0 + 128 + r2) * K + scol;
  const int dst = tid * 8;   // ushort index within buffer

  // fragment reads: row = base16 + l16, (row>>1)&3 == (l16>>1)&3
  const int swzr = (quad * 8) ^ (((l16 >> 1) & 3) * 8);
  const int aoff = (wm * 128 + l16) * 32 + swzr;
  const int boff = 8192 + (wn * 64 + l16) * 32 + swzr;

  f32x4 acc[8][4];
  #pragma unroll
  for (int i = 0; i < 8; ++i)
    #pragma unroll
    for (int j = 0; j < 4; ++j) acc[i][j] = (f32x4){0.f, 0.f, 0.f, 0.f};

  const int NT = K >> 5;   // BK=32; NT >= 4 for both call sites (32, 16)

  // prologue: stage tiles 0,1,2
  #pragma unroll
  for (int s = 0; s < 3; ++s) {
    unsigned short* sb = &sm[s * 16384];
    const long ko = (long)s * 32;
    gload_lds16(a0p + ko, sb + dst);
    gload_lds16(a1p + ko, sb + 4096 + dst);
    gload_lds16(b0p + ko, sb + 8192 + dst);
    gload_lds16(b1p + ko, sb + 12288 + dst);
  }
  asm volatile("s_waitcnt vmcnt(8)" ::: "memory");   // tile 0 landed; 1,2 in flight
  __builtin_amdgcn_s_barrier();
  __builtin_amdgcn_sched_barrier(0);

  int t = 0;
  for (; t < NT - 3; ++t) G4_TILE(t, true, "vmcnt(8)");   // stage t+3; t+1 landed
  G4_TILE(t, false, "vmcnt(4)"); ++t;                     // NT-3: NT-2 landed
  G4_TILE(t, false, "vmcnt(0)"); ++t;                     // NT-2: NT-1 landed
  G4_TILE(t, false, "vmcnt(0)");                          // NT-1 (barrier fences epi)

  // ---------------- epilogue via LDS (two 128-row passes) --------------------
  unsigned short* epi = sm;
  #pragma unroll
  for (int h = 0; h < 2; ++h) {
    if (wm == h) {
      #pragma unroll
      for (int fm = 0; fm < 8; ++fm)
        #pragma unroll
        for (int fn = 0; fn < 4; ++fn)
          #pragma unroll
          for (int r = 0; r < 4; ++r)
            epi[(fm * 16 + quad * 4 + r) * EPSW + wn * 64 + fn * 16 + l16] = f2bf(acc[fm][fn][r]);
    }
    __syncthreads();
    if (MODE == 0) {
      #pragma unroll
      for (int i = tid; i < 4096; i += 512) {
        int row = i >> 5, cc = (i & 31) * 8;
        uint4 v = *(const uint4*)&epi[row * EPSW + cc];
        *(uint4*)&Cb[(long)(m0 + h * 128 + row) * N + n0 + cc] = v;
      }
    } else {
      #pragma unroll
      for (int i = tid; i < 8192; i += 512) {
        int row = i >> 6, cc = (i & 63) * 4;
        long g = (long)(m0 + h * 128 + row) * N + n0 + cc;
        float4 rv = *(const float4*)&resid[g];
        uint2 pv = *(const uint2*)&epi[row * EPSW + cc];
        float4 ov;
        ov.x = bf2f((unsigned short)(pv.x & 0xffffu)) + rv.x;
        ov.y = bf2f((unsigned short)(pv.x >> 16))     + rv.y;
        ov.z = bf2f((unsigned short)(pv.y & 0xffffu)) + rv.z;
        ov.w = bf2f((unsigned short)(pv.y >> 16))     + rv.w;
        *(float4*)&Cf[g] = ov;
      }
    }
    __syncthreads();
  }
}

// ---------------- K3: fused per-chunk prep + intra-chunk attention -----------
#define TS 72
__global__ __launch_bounds__(256) void prep_intra_kernel(const unsigned short* __restrict__ Cb,
                                                         const float* __restrict__ ba,
                                                         unsigned short* __restrict__ qt,
                                                         float* __restrict__ Dvec,
                                                         unsigned short* __restrict__ Ointra,
                                                         unsigned short* __restrict__ Tt) {
  const int bhc = blockIdx.x;
  const int c = bhc & 63, bh = bhc >> 6;
  const int h = bh & 7, b = bh >> 3;
  const int tid = threadIdx.x;
  __shared__ __align__(16) unsigned short Qb[4096], Kb[4096], Vb[4096], lamB[4096];
  __shared__ __align__(16) unsigned short Vt[64 * TS], Kt[64 * TS];
  __shared__ float rnF[64], lendF[64];
  const long rowbase = ((long)(b * 4096 + c * 64)) * 2048;
  const int hoff = h * 64;

  if (tid < 64) rnF[tid] = 0.f;
  __syncthreads();

  #pragma unroll
  for (int chunk = 0; chunk < 2; ++chunk) {
    int u = chunk * 256 + tid;
    int t = u >> 3, p = u & 7;
    long g = rowbase + (long)t * 2048 + hoff + p * 8;
    uint4 q4 = *(const uint4*)(Cb + g);
    uint4 k4 = *(const uint4*)(Cb + g + 512);
    uint4 v4 = *(const uint4*)(Cb + g + 1024);
    uint4 a4 = *(const uint4*)(Cb + g + 1536);
    *(uint4*)&Qb[u * 8] = q4;
    *(uint4*)&Kb[u * 8] = k4;
    *(uint4*)&Vb[u * 8] = v4;
    const unsigned short* as_ = (const unsigned short*)&a4;
    unsigned short al[8];
    #pragma unroll
    for (int j = 0; j < 8; ++j) {
      float z = bf2f(as_[j]) + ba[hoff + p * 8 + j];
      al[j] = f2bf(1.f / (1.f + __expf(-z)));
    }
    uint4 pa;
    pa.x = (unsigned)al[0] | ((unsigned)al[1] << 16); pa.y = (unsigned)al[2] | ((unsigned)al[3] << 16);
    pa.z = (unsigned)al[4] | ((unsigned)al[5] << 16); pa.w = (unsigned)al[6] | ((unsigned)al[7] << 16);
    *(uint4*)&lamB[u * 8] = pa;
    const unsigned short* ks = (const unsigned short*)&k4;
    float ssq = 0.f;
    #pragma unroll
    for (int j = 0; j < 8; ++j) { float kv = bf2f(ks[j]); ssq += kv * kv; }
    atomicAdd(&rnF[t], ssq);
  }
  __syncthreads();

  if (tid < 64) {
    int d = tid; float cum = 1.f;
    #pragma unroll
    for (int t = 0; t < 64; ++t) {
      cum *= bf2f(lamB[t * 64 + d]);
      lamB[t * 64 + d] = f2bf(cum);
    }
    Dvec[(long)bhc * 64 + d] = cum;
    lendF[d] = cum;
  } else if (tid < 128) {
    int t = tid - 64;
    rnF[t] = 1.f / fmaxf(sqrtf(rnF[t]), 1e-12f);
  }
  __syncthreads();

  #pragma unroll
  for (int j = 0; j < 16; ++j) {
    int e = j * 256 + tid;
    int t = e >> 6;
    float lam = bf2f(lamB[e]);
    float kn = bf2f(Kb[e]) * rnF[t];
    Qb[e] = f2bf(bf2f(Qb[e]) * lam);
    Kb[e] = f2bf(kn / lam);
  }
  __syncthreads();

  {
    const long obase = (long)bhc * 4096;
    uint4* gq = (uint4*)(qt + obase);
    const uint4* lq = (const uint4*)Qb;
    gq[tid] = lq[tid]; gq[tid + 256] = lq[tid + 256];
  }

  const long base = (long)bhc * 4096;
  const int wave = tid >> 6, lane = tid & 63, quad = lane >> 4, l16 = lane & 15;
  const int mrow = wave * 16 + l16;
  unsigned short* Ps = lamB;

  union { short8 v; short s[8]; } aI;
  aI.v = (short8){0,0,0,0,0,0,0,0};
  {
    int target = ((wave & 1) * 16 + l16) - quad * 8;
    if (target >= 0 && target < 8) aI.s[target] = (short)0x3F80;
  }
  const int bsel = (wave >> 1) * 32;

  {
    short8 a0 = *(const short8*)&Qb[mrow * 64 + quad * 8];
    short8 a1 = *(const short8*)&Qb[mrow * 64 + 32 + quad * 8];
    #pragma unroll
    for (int nt = 0; nt < 4; ++nt) {
      short8 b0 = *(const short8*)&Kb[(nt * 16 + l16) * 64 + quad * 8];
      short8 b1 = *(const short8*)&Kb[(nt * 16 + l16) * 64 + 32 + quad * 8];
      f32x4 acc = (f32x4){0.f, 0.f, 0.f, 0.f};
      acc = __builtin_amdgcn_mfma_f32_16x16x32_bf16(a0, b0, acc, 0, 0, 0);
      acc = __builtin_amdgcn_mfma_f32_16x16x32_bf16(a1, b1, acc, 0, 0, 0);
      #pragma unroll
      for (int r = 0; r < 4; ++r) {
        int t = wave * 16 + quad * 4 + r, u = nt * 16 + l16;
        Ps[t * 64 + u] = (u <= t) ? f2bf(acc[r]) : (unsigned short)0;
      }
    }
  }
  #pragma unroll
  for (int nt = 0; nt < 4; ++nt) {
    short8 bv = *(const short8*)&Vb[(nt * 16 + l16) * 64 + bsel + quad * 8];
    short8 bk = *(const short8*)&Kb[(nt * 16 + l16) * 64 + bsel + quad * 8];
    f32x4 av = (f32x4){0.f, 0.f, 0.f, 0.f};
    f32x4 ak = (f32x4){0.f, 0.f, 0.f, 0.f};
    av = __builtin_amdgcn_mfma_f32_16x16x32_bf16(aI.v, bv, av, 0, 0, 0);
    ak = __builtin_amdgcn_mfma_f32_16x16x32_bf16(aI.v, bk, ak, 0, 0, 0);
    #pragma unroll
    for (int r = 0; r < 4; ++r) {
      int i = wave * 16 + quad * 4 + r, t = nt * 16 + l16;
      Vt[i * TS + t] = f2bf(av[r]);
      Kt[i * TS + t] = f2bf(ak[r]);
    }
  }
  __syncthreads();

  {
    short8 a0 = *(const short8*)&Ps[mrow * 64 + quad * 8];
    short8 a1 = *(const short8*)&Ps[mrow * 64 + 32 + quad * 8];
    #pragma unroll
    for (int nt = 0; nt < 4; ++nt) {
      short8 b0 = *(const short8*)&Vt[(nt * 16 + l16) * TS + quad * 8];
      short8 b1 = *(const short8*)&Vt[(nt * 16 + l16) * TS + 32 + quad * 8];
      f32x4 acc = (f32x4){0.f, 0.f, 0.f, 0.f};
      acc = __builtin_amdgcn_mfma_f32_16x16x32_bf16(a0, b0, acc, 0, 0, 0);
      acc = __builtin_amdgcn_mfma_f32_16x16x32_bf16(a1, b1, acc, 0, 0, 0);
      #pragma unroll
      for (int r = 0; r < 4; ++r) {
        int t = wave * 16 + quad * 4 + r, i = nt * 16 + l16;
        Ointra[base + t * 64 + i] = f2bf(acc[r]);
      }
    }
  }
  {
    short8 a0 = *(const short8*)&Vt[mrow * TS + quad * 8];
    short8 a1 = *(const short8*)&Vt[mrow * TS + 32 + quad * 8];
    #pragma unroll
    for (int nt = 0; nt < 4; ++nt) {
      short8 b0 = *(const short8*)&Kt[(nt * 16 + l16) * TS + quad * 8];
      short8 b1 = *(const short8*)&Kt[(nt * 16 + l16) * TS + 32 + quad * 8];
      f32x4 acc = (f32x4){0.f, 0.f, 0.f, 0.f};
      acc = __builtin_amdgcn_mfma_f32_16x16x32_bf16(a0, b0, acc, 0, 0, 0);
      acc = __builtin_amdgcn_mfma_f32_16x16x32_bf16(a1, b1, acc, 0, 0, 0);
      float le = lendF[nt * 16 + l16];
      #pragma unroll
      for (int r = 0; r < 4; ++r) {
        int i = wave * 16 + quad * 4 + r, j = nt * 16 + l16;
        Tt[base + i * 64 + j] = f2bf(acc[r] * le);
      }
    }
  }
}

// ---------------- K5: chunk-state scan, element-parallel ---------------------
__global__ __launch_bounds__(256) void scan_kernel(const unsigned short* __restrict__ Tt,
                                                   const float* __restrict__ Dvec,
                                                   unsigned short* __restrict__ Sst) {
  const int bh = blockIdx.x;
  const int e = blockIdx.y * 256 + threadIdx.x;
  const int j = e & 63;
  float S = 0.f;
  for (int c = 0; c < 64; ++c) {
    const long idx = ((long)(bh * 64 + c)) * 4096 + e;
    const float dj = Dvec[((long)(bh * 64 + c)) * 64 + j];
    Sst[idx] = f2bf(S);
    S = dj * S + bf2f(Tt[idx]);
  }
}

// ---------------- K6: O = O_intra + q~ @ S_prev --------------------------
__global__ __launch_bounds__(256) void combine_kernel(const unsigned short* __restrict__ qt,
                                                      const unsigned short* __restrict__ Sst,
                                                      const unsigned short* __restrict__ Ointra,
                                                      unsigned short* __restrict__ O) {
  const int bhc = blockIdx.x;
  const int c = bhc & 63, bh = bhc >> 6;
  const int h = bh & 7, b = bh >> 3;
  const long base = (long)bhc * 4096;
  __shared__ __align__(16) unsigned short Qs[4096], Sb[4096];
  const int tid = threadIdx.x;
  {
    const uint4* gq = (const uint4*)(qt + base);  uint4* lq = (uint4*)Qs;
    const uint4* gs = (const uint4*)(Sst + base); uint4* ls = (uint4*)Sb;
    lq[tid] = gq[tid]; lq[tid + 256] = gq[tid + 256];
    ls[tid] = gs[tid]; ls[tid + 256] = gs[tid + 256];
  }
  __syncthreads();
  const int wave = tid >> 6, lane = tid & 63, quad = lane >> 4, l16 = lane & 15;
  const int mrow = wave * 16 + l16;
  short8 a0 = *(const short8*)&Qs[mrow * 64 + quad * 8];
  short8 a1 = *(const short8*)&Qs[mrow * 64 + 32 + quad * 8];
  #pragma unroll
  for (int nt = 0; nt < 4; ++nt) {
    f32x4 acc;
    #pragma unroll
    for (int r = 0; r < 4; ++r) {
      int t = wave * 16 + quad * 4 + r, i = nt * 16 + l16;
      acc[r] = bf2f(Ointra[base + t * 64 + i]);
    }
    short8 b0 = *(const short8*)&Sb[(nt * 16 + l16) * 64 + quad * 8];
    short8 b1 = *(const short8*)&Sb[(nt * 16 + l16) * 64 + 32 + quad * 8];
    acc = __builtin_amdgcn_mfma_f32_16x16x32_bf16(a0, b0, acc, 0, 0, 0);
    acc = __builtin_amdgcn_mfma_f32_16x16x32_bf16(a1, b1, acc, 0, 0, 0);
    #pragma unroll
    for (int r = 0; r < 4; ++r) {
      int t = wave * 16 + quad * 4 + r, i = nt * 16 + l16;
      O[((long)(b * 4096 + c * 64 + t)) * 512 + h * 64 + i] = f2bf(acc[r]);
    }
  }
}

// ---------------- host ----------------
extern "C" void kernel_launch(void* const* d_in, const int* in_sizes, int n_in,
                              void* d_out, int out_size, void* d_ws, size_t ws_size,
                              hipStream_t stream) {
  const float* x     = (const float*)d_in[0];
  const float* Wq    = (const float*)d_in[1];
  const float* Wk    = (const float*)d_in[2];
  const float* Wv    = (const float*)d_in[3];
  const float* Wa    = (const float*)d_in[4];
  const float* ba    = (const float*)d_in[5];
  const float* Wo    = (const float*)d_in[6];
  const float* gamma = (const float*)d_in[7];
  const float* beta  = (const float*)d_in[8];
  float* out = (float*)d_out;

  char* ws = (char*)d_ws;
  const size_t KB = 1024;
  unsigned short* Wt     = (unsigned short*)(ws + 0 * KB);
  unsigned short* Wot    = (unsigned short*)(ws + 4096 * KB);
  float*          Dvec   = (float*)         (ws + 5120 * KB);
  unsigned short* qt     = (unsigned short*)(ws + 5632 * KB);
  unsigned short* Ttb    = (unsigned short*)(ws + 22016 * KB);
  unsigned short* Sst    = (unsigned short*)(ws + 38400 * KB);
  unsigned short* xn     = (unsigned short*)(ws + 54784 * KB);
  unsigned short* Ointra = (unsigned short*)(ws + 54784 * KB);
  unsigned short* Ob     = (unsigned short*)(ws + 71168 * KB);
  unsigned short* Cb     = (unsigned short*)(ws + 87552 * KB);

  init_kernel<<<NTOK + 2048 + 512, 256, 0, stream>>>(x, gamma, beta, Wq, Wk, Wv, Wa, Wo, xn, Wt, Wot);
  gemm4s<0><<<512, 512, 0, stream>>>(xn, Wt, Cb, nullptr, nullptr, NTOK, 2048, 1024);
  prep_intra_kernel<<<NBHC, 256, 0, stream>>>(Cb, ba, qt, Dvec, Ointra, Ttb);
  scan_kernel<<<dim3(32, 16), 256, 0, stream>>>(Ttb, Dvec, Sst);
  combine_kernel<<<NBHC, 256, 0, stream>>>(qt, Sst, Ointra, Ob);
  gemm4s<1><<<256, 512, 0, stream>>>(Ob, Wot, nullptr, out, x, NTOK, 1024, 512);
}

// Round 5
// 312.409 us; speedup vs baseline: 1.0260x; 1.0260x over previous
//
#include <hip/hip_runtime.h>
#include <stdint.h>

#define NTOK   16384      // B*T = 4*4096
#define DM     1024
#define DI     512
#define NH     8
#define DH     64
#define CHUNK  64
#define NCH    64         // T / CHUNK
#define NBHC   2048       // B*H*NCH

using short8 = __attribute__((ext_vector_type(8))) short;
using f32x4  = __attribute__((ext_vector_type(4))) float;

__device__ __forceinline__ unsigned short f2bf(float f) {
  union { float f; unsigned int u; } x; x.f = f;
  unsigned int u = x.u;
  return (unsigned short)((u + 0x7fffu + ((u >> 16) & 1u)) >> 16);
}
__device__ __forceinline__ float bf2f(unsigned short h) {
  union { unsigned int u; float f; } x; x.u = ((unsigned int)h) << 16; return x.f;
}

typedef const __attribute__((address_space(1))) void* gp1_t;
typedef __attribute__((address_space(3))) void* lp3_t;
__device__ __forceinline__ void gload_lds16(const void* g, void* l) {
  __builtin_amdgcn_global_load_lds((gp1_t)g, (lp3_t)l, 16, 0, 0);
}

// ---------------- K0: fused init: LN (blocks 0..16383), W transposes ---------
__global__ __launch_bounds__(256) void init_kernel(const float* __restrict__ x,
                                                   const float* __restrict__ gamma,
                                                   const float* __restrict__ beta,
                                                   const float* __restrict__ Wq,
                                                   const float* __restrict__ Wk,
                                                   const float* __restrict__ Wv,
                                                   const float* __restrict__ Wa,
                                                   const float* __restrict__ Wo,
                                                   unsigned short* __restrict__ xn,
                                                   unsigned short* __restrict__ Wt,
                                                   unsigned short* __restrict__ Wot) {
  const int blk = blockIdx.x, tid = threadIdx.x;
  __shared__ float tile[32][33];
  __shared__ float rs_[4], rss_[4];
  if (blk < NTOK) {
    const int row = blk;
    float4 v = ((const float4*)(x + (long)row * DM))[tid];
    float s  = v.x + v.y + v.z + v.w;
    float ss = v.x * v.x + v.y * v.y + v.z * v.z + v.w * v.w;
    #pragma unroll
    for (int off = 32; off > 0; off >>= 1) { s += __shfl_down(s, off); ss += __shfl_down(ss, off); }
    int wave = tid >> 6, lane = tid & 63;
    if (lane == 0) { rs_[wave] = s; rss_[wave] = ss; }
    __syncthreads();
    s  = rs_[0] + rs_[1] + rs_[2] + rs_[3];
    ss = rss_[0] + rss_[1] + rss_[2] + rss_[3];
    float mu   = s * (1.f / DM);
    float var  = ss * (1.f / DM) - mu * mu;
    float rstd = rsqrtf(var + 1e-5f);
    int idx = tid * 4;
    float xv[4] = {v.x, v.y, v.z, v.w};
    unsigned short o[4];
    #pragma unroll
    for (int j = 0; j < 4; ++j) o[j] = f2bf((xv[j] - mu) * rstd * gamma[idx + j] + beta[idx + j]);
    uint2 pk; pk.x = (unsigned)o[0] | ((unsigned)o[1] << 16); pk.y = (unsigned)o[2] | ((unsigned)o[3] << 16);
    *(uint2*)(xn + (long)row * DM + idx) = pk;
  } else if (blk < NTOK + 2048) {
    const int id = blk - NTOK;
    const int z = id >> 9, r9 = id & 511;
    const float* in = (z == 0) ? Wq : (z == 1) ? Wk : (z == 2) ? Wv : Wa;
    unsigned short* o = Wt + (size_t)z * 512 * 1024;
    int bx = (r9 & 15) * 32, by = (r9 >> 4) * 32;
    int tx = tid & 31, ty = tid >> 5;
    #pragma unroll
    for (int r = ty; r < 32; r += 8) tile[r][tx] = in[(long)(by + r) * 512 + bx + tx];
    __syncthreads();
    #pragma unroll
    for (int r = ty; r < 32; r += 8) o[(long)(bx + r) * 1024 + by + tx] = f2bf(tile[tx][r]);
  } else {
    const int id = blk - NTOK - 2048;
    int bx = (id & 31) * 32, by = (id >> 5) * 32;
    int tx = tid & 31, ty = tid >> 5;
    #pragma unroll
    for (int r = ty; r < 32; r += 8) tile[r][tx] = Wo[(long)(by + r) * 1024 + bx + tx];
    __syncthreads();
    #pragma unroll
    for (int r = ty; r < 32; r += 8) Wot[(long)(bx + r) * 512 + by + tx] = f2bf(tile[tx][r]);
  }
}

// ---------------- GEMM1: C[M][N] = A(bf16 MxK) * Bt(bf16 NxK)^T --------------
// Round-3 structure (best measured): 256x256 tile, BK=32, quad-buffered LDS,
// depth-3 prefetch, counted vmcnt(8), one barrier per K-tile, 8 waves.
// Swizzle: phys_col = logical ^ (((row>>1)&3)<<4) on staging source + ds_read.
#define EPSW 264   // epilogue LDS row stride (ushorts), 256+8
#define G4_TILE(T_, DOSTAGE_, WAITC_)                                         \
  {                                                                           \
    if (DOSTAGE_) {                                                           \
      const int s_ = (T_) + 3;                                                \
      unsigned short* sb_ = &sm[(s_ & 3) * 16384];                            \
      const long ko_ = (long)s_ * 32;                                         \
      gload_lds16(a0p + ko_, sb_ + dst);                                      \
      gload_lds16(a1p + ko_, sb_ + 4096 + dst);                               \
      gload_lds16(b0p + ko_, sb_ + 8192 + dst);                               \
      gload_lds16(b1p + ko_, sb_ + 12288 + dst);                              \
    }                                                                         \
    const unsigned short* cb_ = &sm[((T_) & 3) * 16384];                      \
    short8 av_[8], bv_[4];                                                    \
    _Pragma("unroll")                                                         \
    for (int mt = 0; mt < 8; ++mt) av_[mt] = *(const short8*)&cb_[aoff + mt * 512]; \
    _Pragma("unroll")                                                         \
    for (int nt = 0; nt < 4; ++nt) bv_[nt] = *(const short8*)&cb_[boff + nt * 512]; \
    __builtin_amdgcn_s_setprio(1);                                            \
    _Pragma("unroll")                                                         \
    for (int mt = 0; mt < 8; ++mt)                                            \
      _Pragma("unroll")                                                       \
      for (int nt = 0; nt < 4; ++nt)                                          \
        acc[mt][nt] = __builtin_amdgcn_mfma_f32_16x16x32_bf16(av_[mt], bv_[nt], acc[mt][nt], 0, 0, 0); \
    __builtin_amdgcn_s_setprio(0);                                            \
    asm volatile("s_waitcnt " WAITC_ ::: "memory");                           \
    __builtin_amdgcn_s_barrier();                                             \
    __builtin_amdgcn_sched_barrier(0);                                        \
  }

__global__ __launch_bounds__(512, 2) void gemm1k(const unsigned short* __restrict__ A,
                                                 const unsigned short* __restrict__ Bt,
                                                 unsigned short* __restrict__ Cb,
                                                 int M, int N, int K) {
  __shared__ __align__(16) unsigned short sm[65536];   // 128 KiB
  const int tid = threadIdx.x;
  const int wave = tid >> 6, lane = tid & 63;
  const int quad = lane >> 4, l16 = lane & 15;
  const int wm = wave >> 2, wn = wave & 3;

  const int nwg = gridDim.x;
  const int cpx = nwg >> 3;
  const int bid = blockIdx.x;
  const int swz = (bid & 7) * cpx + (bid >> 3);
  const int m0 = (swz & 63) * 256;
  const int n0 = (swz >> 6) * 256;

  const int r2 = tid >> 2;
  const int scol = ((tid & 3) * 8) ^ (((tid >> 3) & 3) * 8);   // ushort units, < 32
  const unsigned short* a0p = A + (long)(m0 + r2) * K + scol;
  const unsigned short* a1p = A + (long)(m0 + 128 + r2) * K + scol;
  const unsigned short* b0p = Bt + (long)(n0 + r2) * K + scol;
  const unsigned short* b1p = Bt + (long)(n0 + 128 + r2) * K + scol;
  const int dst = tid * 8;

  const int swzr = (quad * 8) ^ (((l16 >> 1) & 3) * 8);
  const int aoff = (wm * 128 + l16) * 32 + swzr;
  const int boff = 8192 + (wn * 64 + l16) * 32 + swzr;

  f32x4 acc[8][4];
  #pragma unroll
  for (int i = 0; i < 8; ++i)
    #pragma unroll
    for (int j = 0; j < 4; ++j) acc[i][j] = (f32x4){0.f, 0.f, 0.f, 0.f};

  const int NT = K >> 5;

  #pragma unroll
  for (int s = 0; s < 3; ++s) {
    unsigned short* sb = &sm[s * 16384];
    const long ko = (long)s * 32;
    gload_lds16(a0p + ko, sb + dst);
    gload_lds16(a1p + ko, sb + 4096 + dst);
    gload_lds16(b0p + ko, sb + 8192 + dst);
    gload_lds16(b1p + ko, sb + 12288 + dst);
  }
  asm volatile("s_waitcnt vmcnt(8)" ::: "memory");
  __builtin_amdgcn_s_barrier();
  __builtin_amdgcn_sched_barrier(0);

  int t = 0;
  for (; t < NT - 3; ++t) G4_TILE(t, true, "vmcnt(8)");
  G4_TILE(t, false, "vmcnt(4)"); ++t;
  G4_TILE(t, false, "vmcnt(0)"); ++t;
  G4_TILE(t, false, "vmcnt(0)");

  unsigned short* epi = sm;
  #pragma unroll
  for (int h = 0; h < 2; ++h) {
    if (wm == h) {
      #pragma unroll
      for (int fm = 0; fm < 8; ++fm)
        #pragma unroll
        for (int fn = 0; fn < 4; ++fn)
          #pragma unroll
          for (int r = 0; r < 4; ++r)
            epi[(fm * 16 + quad * 4 + r) * EPSW + wn * 64 + fn * 16 + l16] = f2bf(acc[fm][fn][r]);
    }
    __syncthreads();
    #pragma unroll
    for (int i = tid; i < 4096; i += 512) {
      int row = i >> 5, cc = (i & 31) * 8;
      uint4 v = *(const uint4*)&epi[row * EPSW + cc];
      *(uint4*)&Cb[(long)(m0 + h * 128 + row) * N + n0 + cc] = v;
    }
    __syncthreads();
  }
}

// ---------------- GEMM2: Cf = A*Bt^T + resid (fp32 out), 128x128 tile --------
// Same schedule/swizzle as gemm1k but 256 threads (4 waves 2x2, 64x64/wave),
// 64 KiB LDS -> 2 WG/CU, grid 1024 WGs (4 rounds) so main-loops and fp32
// epilogues overlap across co-resident blocks (round-4 lesson: gemm2's 81 us
// was 1-WG/CU serialization, not compute).
__global__ __launch_bounds__(256, 2) void gemm2k(const unsigned short* __restrict__ A,
                                                 const unsigned short* __restrict__ Bt,
                                                 float* __restrict__ Cf,
                                                 const float* __restrict__ resid,
                                                 int M, int N, int K) {
  __shared__ __align__(16) unsigned short sm[32768];   // 64 KiB
  const int tid = threadIdx.x;
  const int wave = tid >> 6, lane = tid & 63;
  const int quad = lane >> 4, l16 = lane & 15;
  const int wm = wave >> 1, wn = wave & 1;

  const int nwg = gridDim.x;            // 1024
  const int cpx = nwg >> 3;             // 128
  const int bid = blockIdx.x;
  const int swz = (bid & 7) * cpx + (bid >> 3);
  const int m0 = (swz & 127) * 128;     // 128 m-tiles
  const int n0 = (swz >> 7) * 128;      // 8 n-tiles

  const int r2 = tid >> 2;              // 0..63
  const int scol = ((tid & 3) * 8) ^ (((tid >> 3) & 3) * 8);
  const unsigned short* a0p = A + (long)(m0 + r2) * K + scol;
  const unsigned short* a1p = A + (long)(m0 + 64 + r2) * K + scol;
  const unsigned short* b0p = Bt + (long)(n0 + r2) * K + scol;
  const unsigned short* b1p = Bt + (long)(n0 + 64 + r2) * K + scol;
  const int dst = tid * 8;              // 0..2047

  const int swzr = (quad * 8) ^ (((l16 >> 1) & 3) * 8);
  const int aoff = wm * 2048 + l16 * 32 + swzr;          // + mt*512
  const int boff = 4096 + wn * 2048 + l16 * 32 + swzr;   // + nt*512

  f32x4 acc[4][4];
  #pragma unroll
  for (int i = 0; i < 4; ++i)
    #pragma unroll
    for (int j = 0; j < 4; ++j) acc[i][j] = (f32x4){0.f, 0.f, 0.f, 0.f};

  const int NT = K >> 5;   // 16

  #pragma unroll
  for (int s = 0; s < 3; ++s) {
    unsigned short* sb = &sm[s * 8192];
    const long ko = (long)s * 32;
    gload_lds16(a0p + ko, sb + dst);
    gload_lds16(a1p + ko, sb + 2048 + dst);
    gload_lds16(b0p + ko, sb + 4096 + dst);
    gload_lds16(b1p + ko, sb + 6144 + dst);
  }
  asm volatile("s_waitcnt vmcnt(8)" ::: "memory");
  __builtin_amdgcn_s_barrier();
  __builtin_amdgcn_sched_barrier(0);

#define G2_TILE(T_, DOSTAGE_, WAITC_)                                         \
  {                                                                           \
    if (DOSTAGE_) {                                                           \
      const int s_ = (T_) + 3;                                                \
      unsigned short* sb_ = &sm[(s_ & 3) * 8192];                             \
      const long ko_ = (long)s_ * 32;                                         \
      gload_lds16(a0p + ko_, sb_ + dst);                                      \
      gload_lds16(a1p + ko_, sb_ + 2048 + dst);                               \
      gload_lds16(b0p + ko_, sb_ + 4096 + dst);                               \
      gload_lds16(b1p + ko_, sb_ + 6144 + dst);                               \
    }                                                                         \
    const unsigned short* cb_ = &sm[((T_) & 3) * 8192];                       \
    short8 av_[4], bv_[4];                                                    \
    _Pragma("unroll")                                                         \
    for (int mt = 0; mt < 4; ++mt) av_[mt] = *(const short8*)&cb_[aoff + mt * 512]; \
    _Pragma("unroll")                                                         \
    for (int nt = 0; nt < 4; ++nt) bv_[nt] = *(const short8*)&cb_[boff + nt * 512]; \
    __builtin_amdgcn_s_setprio(1);                                            \
    _Pragma("unroll")                                                         \
    for (int mt = 0; mt < 4; ++mt)                                            \
      _Pragma("unroll")                                                       \
      for (int nt = 0; nt < 4; ++nt)                                          \
        acc[mt][nt] = __builtin_amdgcn_mfma_f32_16x16x32_bf16(av_[mt], bv_[nt], acc[mt][nt], 0, 0, 0); \
    __builtin_amdgcn_s_setprio(0);                                            \
    asm volatile("s_waitcnt " WAITC_ ::: "memory");                           \
    __builtin_amdgcn_s_barrier();                                             \
    __builtin_amdgcn_sched_barrier(0);                                        \
  }

  int t = 0;
  for (; t < NT - 3; ++t) G2_TILE(t, true, "vmcnt(8)");
  G2_TILE(t, false, "vmcnt(4)"); ++t;
  G2_TILE(t, false, "vmcnt(0)"); ++t;
  G2_TILE(t, false, "vmcnt(0)");

  // epilogue: 128x136 ushort staging (34.8 KB), all waves at once
  unsigned short* epi = sm;
  #pragma unroll
  for (int mt = 0; mt < 4; ++mt)
    #pragma unroll
    for (int nt = 0; nt < 4; ++nt)
      #pragma unroll
      for (int r = 0; r < 4; ++r)
        epi[(wm * 64 + mt * 16 + quad * 4 + r) * 136 + wn * 64 + nt * 16 + l16] = f2bf(acc[mt][nt][r]);
  __syncthreads();
  #pragma unroll
  for (int i = tid; i < 4096; i += 256) {
    int row = i >> 5, cc = (i & 31) * 4;
    long g = (long)(m0 + row) * N + n0 + cc;
    float4 rv = *(const float4*)&resid[g];
    uint2 pv = *(const uint2*)&epi[row * 136 + cc];
    float4 ov;
    ov.x = bf2f((unsigned short)(pv.x & 0xffffu)) + rv.x;
    ov.y = bf2f((unsigned short)(pv.x >> 16))     + rv.y;
    ov.z = bf2f((unsigned short)(pv.y & 0xffffu)) + rv.z;
    ov.w = bf2f((unsigned short)(pv.y >> 16))     + rv.w;
    *(float4*)&Cf[g] = ov;
  }
}

// ---------------- K3: fused per-chunk prep + intra-chunk attention -----------
#define TS 72
__global__ __launch_bounds__(256) void prep_intra_kernel(const unsigned short* __restrict__ Cb,
                                                         const float* __restrict__ ba,
                                                         unsigned short* __restrict__ qt,
                                                         float* __restrict__ Dvec,
                                                         unsigned short* __restrict__ Ointra,
                                                         unsigned short* __restrict__ Tt) {
  const int bhc = blockIdx.x;
  const int c = bhc & 63, bh = bhc >> 6;
  const int h = bh & 7, b = bh >> 3;
  const int tid = threadIdx.x;
  __shared__ __align__(16) unsigned short Qb[4096], Kb[4096], Vb[4096], lamB[4096];
  __shared__ __align__(16) unsigned short Vt[64 * TS], Kt[64 * TS];
  __shared__ float rnF[64], lendF[64];
  const long rowbase = ((long)(b * 4096 + c * 64)) * 2048;
  const int hoff = h * 64;

  if (tid < 64) rnF[tid] = 0.f;
  __syncthreads();

  #pragma unroll
  for (int chunk = 0; chunk < 2; ++chunk) {
    int u = chunk * 256 + tid;
    int t = u >> 3, p = u & 7;
    long g = rowbase + (long)t * 2048 + hoff + p * 8;
    uint4 q4 = *(const uint4*)(Cb + g);
    uint4 k4 = *(const uint4*)(Cb + g + 512);
    uint4 v4 = *(const uint4*)(Cb + g + 1024);
    uint4 a4 = *(const uint4*)(Cb + g + 1536);
    *(uint4*)&Qb[u * 8] = q4;
    *(uint4*)&Kb[u * 8] = k4;
    *(uint4*)&Vb[u * 8] = v4;
    const unsigned short* as_ = (const unsigned short*)&a4;
    unsigned short al[8];
    #pragma unroll
    for (int j = 0; j < 8; ++j) {
      float z = bf2f(as_[j]) + ba[hoff + p * 8 + j];
      al[j] = f2bf(1.f / (1.f + __expf(-z)));
    }
    uint4 pa;
    pa.x = (unsigned)al[0] | ((unsigned)al[1] << 16); pa.y = (unsigned)al[2] | ((unsigned)al[3] << 16);
    pa.z = (unsigned)al[4] | ((unsigned)al[5] << 16); pa.w = (unsigned)al[6] | ((unsigned)al[7] << 16);
    *(uint4*)&lamB[u * 8] = pa;
    const unsigned short* ks = (const unsigned short*)&k4;
    float ssq = 0.f;
    #pragma unroll
    for (int j = 0; j < 8; ++j) { float kv = bf2f(ks[j]); ssq += kv * kv; }
    atomicAdd(&rnF[t], ssq);
  }
  __syncthreads();

  if (tid < 64) {
    int d = tid; float cum = 1.f;
    #pragma unroll
    for (int t = 0; t < 64; ++t) {
      cum *= bf2f(lamB[t * 64 + d]);
      lamB[t * 64 + d] = f2bf(cum);
    }
    Dvec[(long)bhc * 64 + d] = cum;
    lendF[d] = cum;
  } else if (tid < 128) {
    int t = tid - 64;
    rnF[t] = 1.f / fmaxf(sqrtf(rnF[t]), 1e-12f);
  }
  __syncthreads();

  #pragma unroll
  for (int j = 0; j < 16; ++j) {
    int e = j * 256 + tid;
    int t = e >> 6;
    float lam = bf2f(lamB[e]);
    float kn = bf2f(Kb[e]) * rnF[t];
    Qb[e] = f2bf(bf2f(Qb[e]) * lam);
    Kb[e] = f2bf(kn / lam);
  }
  __syncthreads();

  {
    const long obase = (long)bhc * 4096;
    uint4* gq = (uint4*)(qt + obase);
    const uint4* lq = (const uint4*)Qb;
    gq[tid] = lq[tid]; gq[tid + 256] = lq[tid + 256];
  }

  const long base = (long)bhc * 4096;
  const int wave = tid >> 6, lane = tid & 63, quad = lane >> 4, l16 = lane & 15;
  const int mrow = wave * 16 + l16;
  unsigned short* Ps = lamB;

  union { short8 v; short s[8]; } aI;
  aI.v = (short8){0,0,0,0,0,0,0,0};
  {
    int target = ((wave & 1) * 16 + l16) - quad * 8;
    if (target >= 0 && target < 8) aI.s[target] = (short)0x3F80;
  }
  const int bsel = (wave >> 1) * 32;

  {
    short8 a0 = *(const short8*)&Qb[mrow * 64 + quad * 8];
    short8 a1 = *(const short8*)&Qb[mrow * 64 + 32 + quad * 8];
    #pragma unroll
    for (int nt = 0; nt < 4; ++nt) {
      short8 b0 = *(const short8*)&Kb[(nt * 16 + l16) * 64 + quad * 8];
      short8 b1 = *(const short8*)&Kb[(nt * 16 + l16) * 64 + 32 + quad * 8];
      f32x4 acc = (f32x4){0.f, 0.f, 0.f, 0.f};
      acc = __builtin_amdgcn_mfma_f32_16x16x32_bf16(a0, b0, acc, 0, 0, 0);
      acc = __builtin_amdgcn_mfma_f32_16x16x32_bf16(a1, b1, acc, 0, 0, 0);
      #pragma unroll
      for (int r = 0; r < 4; ++r) {
        int t = wave * 16 + quad * 4 + r, u = nt * 16 + l16;
        Ps[t * 64 + u] = (u <= t) ? f2bf(acc[r]) : (unsigned short)0;
      }
    }
  }
  #pragma unroll
  for (int nt = 0; nt < 4; ++nt) {
    short8 bv = *(const short8*)&Vb[(nt * 16 + l16) * 64 + bsel + quad * 8];
    short8 bk = *(const short8*)&Kb[(nt * 16 + l16) * 64 + bsel + quad * 8];
    f32x4 av = (f32x4){0.f, 0.f, 0.f, 0.f};
    f32x4 ak = (f32x4){0.f, 0.f, 0.f, 0.f};
    av = __builtin_amdgcn_mfma_f32_16x16x32_bf16(aI.v, bv, av, 0, 0, 0);
    ak = __builtin_amdgcn_mfma_f32_16x16x32_bf16(aI.v, bk, ak, 0, 0, 0);
    #pragma unroll
    for (int r = 0; r < 4; ++r) {
      int i = wave * 16 + quad * 4 + r, t = nt * 16 + l16;
      Vt[i * TS + t] = f2bf(av[r]);
      Kt[i * TS + t] = f2bf(ak[r]);
    }
  }
  __syncthreads();

  // O_intra = P V -> stage into Vb (dead); Tt -> stage into Kb (dead)
  {
    short8 a0 = *(const short8*)&Ps[mrow * 64 + quad * 8];
    short8 a1 = *(const short8*)&Ps[mrow * 64 + 32 + quad * 8];
    #pragma unroll
    for (int nt = 0; nt < 4; ++nt) {
      short8 b0 = *(const short8*)&Vt[(nt * 16 + l16) * TS + quad * 8];
      short8 b1 = *(const short8*)&Vt[(nt * 16 + l16) * TS + 32 + quad * 8];
      f32x4 acc = (f32x4){0.f, 0.f, 0.f, 0.f};
      acc = __builtin_amdgcn_mfma_f32_16x16x32_bf16(a0, b0, acc, 0, 0, 0);
      acc = __builtin_amdgcn_mfma_f32_16x16x32_bf16(a1, b1, acc, 0, 0, 0);
      #pragma unroll
      for (int r = 0; r < 4; ++r) {
        int t = wave * 16 + quad * 4 + r, i = nt * 16 + l16;
        Vb[t * 64 + i] = f2bf(acc[r]);
      }
    }
  }
  {
    short8 a0 = *(const short8*)&Vt[mrow * TS + quad * 8];
    short8 a1 = *(const short8*)&Vt[mrow * TS + 32 + quad * 8];
    #pragma unroll
    for (int nt = 0; nt < 4; ++nt) {
      short8 b0 = *(const short8*)&Kt[(nt * 16 + l16) * TS + quad * 8];
      short8 b1 = *(const short8*)&Kt[(nt * 16 + l16) * TS + 32 + quad * 8];
      f32x4 acc = (f32x4){0.f, 0.f, 0.f, 0.f};
      acc = __builtin_amdgcn_mfma_f32_16x16x32_bf16(a0, b0, acc, 0, 0, 0);
      acc = __builtin_amdgcn_mfma_f32_16x16x32_bf16(a1, b1, acc, 0, 0, 0);
      float le = lendF[nt * 16 + l16];
      #pragma unroll
      for (int r = 0; r < 4; ++r) {
        int i = wave * 16 + quad * 4 + r, j = nt * 16 + l16;
        Kb[i * 64 + j] = f2bf(acc[r] * le);
      }
    }
  }
  __syncthreads();
  // vectorized global writes (16B) from the staged tiles
  {
    const uint4* ov = (const uint4*)Vb; uint4* og = (uint4*)(Ointra + base);
    const uint4* tv = (const uint4*)Kb; uint4* tg = (uint4*)(Tt + base);
    og[tid] = ov[tid]; og[tid + 256] = ov[tid + 256];
    tg[tid] = tv[tid]; tg[tid + 256] = tv[tid + 256];
  }
}

// ---------------- K5: chunk-state scan, element-parallel ---------------------
__global__ __launch_bounds__(256) void scan_kernel(const unsigned short* __restrict__ Tt,
                                                   const float* __restrict__ Dvec,
                                                   unsigned short* __restrict__ Sst) {
  const int bh = blockIdx.x;
  const int e = blockIdx.y * 256 + threadIdx.x;
  const int j = e & 63;
  float S = 0.f;
  for (int c = 0; c < 64; ++c) {
    const long idx = ((long)(bh * 64 + c)) * 4096 + e;
    const float dj = Dvec[((long)(bh * 64 + c)) * 64 + j];
    Sst[idx] = f2bf(S);
    S = dj * S + bf2f(Tt[idx]);
  }
}

// ---------------- K6: O = O_intra + q~ @ S_prev --------------------------
__global__ __launch_bounds__(256) void combine_kernel(const unsigned short* __restrict__ qt,
                                                      const unsigned short* __restrict__ Sst,
                                                      const unsigned short* __restrict__ Ointra,
                                                      unsigned short* __restrict__ O) {
  const int bhc = blockIdx.x;
  const int c = bhc & 63, bh = bhc >> 6;
  const int h = bh & 7, b = bh >> 3;
  const long base = (long)bhc * 4096;
  __shared__ __align__(16) unsigned short Qs[4096], Sb[4096], Os[4096];
  const int tid = threadIdx.x;
  {
    const uint4* gq = (const uint4*)(qt + base);     uint4* lq = (uint4*)Qs;
    const uint4* gs = (const uint4*)(Sst + base);    uint4* ls = (uint4*)Sb;
    const uint4* go = (const uint4*)(Ointra + base); uint4* lo = (uint4*)Os;
    lq[tid] = gq[tid]; lq[tid + 256] = gq[tid + 256];
    ls[tid] = gs[tid]; ls[tid + 256] = gs[tid + 256];
    lo[tid] = go[tid]; lo[tid + 256] = go[tid + 256];
  }
  __syncthreads();
  const int wave = tid >> 6, lane = tid & 63, quad = lane >> 4, l16 = lane & 15;
  const int mrow = wave * 16 + l16;
  short8 a0 = *(const short8*)&Qs[mrow * 64 + quad * 8];
  short8 a1 = *(const short8*)&Qs[mrow * 64 + 32 + quad * 8];
  #pragma unroll
  for (int nt = 0; nt < 4; ++nt) {
    f32x4 acc;
    #pragma unroll
    for (int r = 0; r < 4; ++r) {
      int t = wave * 16 + quad * 4 + r, i = nt * 16 + l16;
      acc[r] = bf2f(Os[t * 64 + i]);
    }
    short8 b0 = *(const short8*)&Sb[(nt * 16 + l16) * 64 + quad * 8];
    short8 b1 = *(const short8*)&Sb[(nt * 16 + l16) * 64 + 32 + quad * 8];
    acc = __builtin_amdgcn_mfma_f32_16x16x32_bf16(a0, b0, acc, 0, 0, 0);
    acc = __builtin_amdgcn_mfma_f32_16x16x32_bf16(a1, b1, acc, 0, 0, 0);
    #pragma unroll
    for (int r = 0; r < 4; ++r) {
      int t = wave * 16 + quad * 4 + r, i = nt * 16 + l16;
      O[((long)(b * 4096 + c * 64 + t)) * 512 + h * 64 + i] = f2bf(acc[r]);
    }
  }
}

// ---------------- host ----------------
extern "C" void kernel_launch(void* const* d_in, const int* in_sizes, int n_in,
                              void* d_out, int out_size, void* d_ws, size_t ws_size,
                              hipStream_t stream) {
  const float* x     = (const float*)d_in[0];
  const float* Wq    = (const float*)d_in[1];
  const float* Wk    = (const float*)d_in[2];
  const float* Wv    = (const float*)d_in[3];
  const float* Wa    = (const float*)d_in[4];
  const float* ba    = (const float*)d_in[5];
  const float* Wo    = (const float*)d_in[6];
  const float* gamma = (const float*)d_in[7];
  const float* beta  = (const float*)d_in[8];
  float* out = (float*)d_out;

  char* ws = (char*)d_ws;
  const size_t KB = 1024;
  unsigned short* Wt     = (unsigned short*)(ws + 0 * KB);
  unsigned short* Wot    = (unsigned short*)(ws + 4096 * KB);
  float*          Dvec   = (float*)         (ws + 5120 * KB);
  unsigned short* qt     = (unsigned short*)(ws + 5632 * KB);
  unsigned short* Ttb    = (unsigned short*)(ws + 22016 * KB);
  unsigned short* Sst    = (unsigned short*)(ws + 38400 * KB);
  unsigned short* xn     = (unsigned short*)(ws + 54784 * KB);
  unsigned short* Ointra = (unsigned short*)(ws + 54784 * KB);
  unsigned short* Ob     = (unsigned short*)(ws + 71168 * KB);
  unsigned short* Cb     = (unsigned short*)(ws + 87552 * KB);

  init_kernel<<<NTOK + 2048 + 512, 256, 0, stream>>>(x, gamma, beta, Wq, Wk, Wv, Wa, Wo, xn, Wt, Wot);
  gemm1k<<<512, 512, 0, stream>>>(xn, Wt, Cb, NTOK, 2048, 1024);
  prep_intra_kernel<<<NBHC, 256, 0, stream>>>(Cb, ba, qt, Dvec, Ointra, Ttb);
  scan_kernel<<<dim3(32, 16), 256, 0, stream>>>(Ttb, Dvec, Sst);
  combine_kernel<<<NBHC, 256, 0, stream>>>(qt, Sst, Ointra, Ob);
  gemm2k<<<1024, 256, 0, stream>>>(Ob, Wot, out, x, NTOK, 1024, 512);
}